// Round 1
// baseline (293.203 us; speedup 1.0000x reference)
//
#include <hip/hip_runtime.h>

// ---- problem constants ----
#define DM    1024
#define LSEQ  4096
#define BATCH 4
#define MROWS (BATCH * LSEQ)           // 16384 rows
#define MD    ((size_t)MROWS * DM)     // 16,777,216 elems
#define DD    ((size_t)DM * DM)        // 1,048,576 elems
#define CHUNK 32
#define NCH   (LSEQ / CHUNK)           // 128 chunks
#define NCHAIN (BATCH * DM)            // 4096 scan chains

typedef __attribute__((ext_vector_type(4))) float  f32x4;
typedef __attribute__((ext_vector_type(8))) __bf16 bf16x8;
typedef __attribute__((ext_vector_type(4))) __bf16 bf16x4;

// async global->LDS, 16B per lane (wave-uniform LDS base + lane*16 semantics;
// our LDS layout is linear in thread order so per-lane &lds[e] matches HW)
__device__ __forceinline__ void gload_lds16(const void* g, void* l) {
  __builtin_amdgcn_global_load_lds(
      (const __attribute__((address_space(1))) void*)g,
      (__attribute__((address_space(3))) void*)l, 16, 0, 0);
}

// ---- fp32 -> bf16 convert, 4 elems/thread ----
__global__ __launch_bounds__(256) void cvt_bf16(const float* __restrict__ in,
                                                __bf16* __restrict__ out) {
  size_t i = ((size_t)blockIdx.x * 256 + threadIdx.x) * 4;
  f32x4 f = *(const f32x4*)(in + i);
  bf16x4 o;
#pragma unroll
  for (int j = 0; j < 4; ++j) o[j] = (__bf16)f[j];
  *(bf16x4*)(out + i) = o;
}

// ---- bf16 NT GEMM: C[m][n] = sum_k A[m][k] * W[n][k]; M=16384(x128 tiles),
// N=K=1024. m97 structure: 128x128 tile, BK=32, 256 thr, global_load_lds w16.
// blockIdx.z selects (W, C) pair at stride DD / MD (for fused q/v/g GEMM).
template <typename OutT>
__global__ __launch_bounds__(256) void gemm_nt(const __bf16* __restrict__ A,
                                               const __bf16* __restrict__ Wb,
                                               OutT* __restrict__ Cb) {
  constexpr int K = DM, N = DM;
  const __bf16* Wp = Wb + (size_t)blockIdx.z * DD;
  OutT* Cp = Cb + (size_t)blockIdx.z * MD;
  const int m0 = blockIdx.y * 128, n0 = blockIdx.x * 128;

  __shared__ __bf16 As[128 * 32];
  __shared__ __bf16 Bs[128 * 32];

  const int t = threadIdx.x;
  const int lane = t & 63, wv = t >> 6;
  const int wm = (wv >> 1) * 64, wn = (wv & 1) * 64;
  const int lrow = lane & 15, koff = (lane >> 4) * 8;

  f32x4 acc[4][4] = {};

  for (int k0 = 0; k0 < K; k0 += 32) {
    // stage 128x32 A-tile and B-tile: 2 issues each, 16B/lane, linear LDS
#pragma unroll
    for (int j = 0; j < 2; ++j) {
      int e = t * 8 + j * 2048;          // element index in tile
      int r = e >> 5, cc = e & 31;       // row, col within tile
      gload_lds16(A + (size_t)(m0 + r) * K + k0 + cc, &As[e]);
      gload_lds16(Wp + (size_t)(n0 + r) * K + k0 + cc, &Bs[e]);
    }
    __syncthreads();

    bf16x8 af[4], bfr[4];
#pragma unroll
    for (int i = 0; i < 4; ++i) {
      af[i]  = *(const bf16x8*)&As[(wm + i * 16 + lrow) * 32 + koff];
      bfr[i] = *(const bf16x8*)&Bs[(wn + i * 16 + lrow) * 32 + koff];
    }
#pragma unroll
    for (int mi = 0; mi < 4; ++mi)
#pragma unroll
      for (int ni = 0; ni < 4; ++ni)
        acc[mi][ni] = __builtin_amdgcn_mfma_f32_16x16x32_bf16(
            af[mi], bfr[ni], acc[mi][ni], 0, 0, 0);
    __syncthreads();
  }

  // C/D layout: col = lane&15, row = (lane>>4)*4 + j   [m89-verified]
#pragma unroll
  for (int mi = 0; mi < 4; ++mi) {
    int r0 = m0 + wm + mi * 16 + (lane >> 4) * 4;
#pragma unroll
    for (int ni = 0; ni < 4; ++ni) {
      int ccol = n0 + wn + ni * 16 + (lane & 15);
#pragma unroll
      for (int j = 0; j < 4; ++j) {
        float v = acc[mi][ni][j];
        if constexpr (__is_same(OutT, float))
          Cp[(size_t)(r0 + j) * N + ccol] = v;
        else
          Cp[(size_t)(r0 + j) * N + ccol] = (__bf16)v;
      }
    }
  }
}

// ---- retention scan pass1: per (b, chunk, 4-chan group) local scan ----
// st[b,t,d] = local prefix (zero init at chunk start); csum[c][chain] = chunk end state
__global__ __launch_bounds__(256) void scan1(const __bf16* __restrict__ v,
                                             float* __restrict__ st,
                                             float* __restrict__ csum,
                                             const float* __restrict__ decay) {
  int tid = blockIdx.x * 256 + threadIdx.x;   // 0 .. 131071
  int dg = tid & 255;                         // d-group (4 channels)
  int b  = (tid >> 8) & 3;
  int c  = tid >> 10;                         // 0..127
  int d0 = dg * 4;
  float lam = decay[((d0 >> 6) << 1) + 1];    // decay[h,1,0]
  f32x4 s = {0.f, 0.f, 0.f, 0.f};
  size_t base = ((size_t)b * LSEQ + (size_t)c * CHUNK) * DM + d0;
  for (int t = 0; t < CHUNK; ++t) {
    bf16x4 vv = *(const bf16x4*)(v + base);
    f32x4 vf = {(float)vv[0], (float)vv[1], (float)vv[2], (float)vv[3]};
    s = lam * s + vf;
    *(f32x4*)(st + base) = s;
    base += DM;
  }
  *(f32x4*)(csum + (size_t)c * NCHAIN + b * DM + d0) = s;
}

// ---- pass2: carry[c][chain] = state entering chunk c ----
__global__ __launch_bounds__(256) void scan2(const float* __restrict__ csum,
                                             float* __restrict__ carry,
                                             const float* __restrict__ decay) {
  int i = blockIdx.x * 256 + threadIdx.x;   // 0..1023
  int ch0 = i * 4;
  int d0 = ch0 & (DM - 1);
  float lam = decay[((d0 >> 6) << 1) + 1];
  // lam^CHUNK (CHUNK=32) by repeated squaring
  float l2 = lam * lam, l4 = l2 * l2, l8 = l4 * l4, l16 = l8 * l8;
  float lamC = l16 * l16;
  f32x4 cs = {0.f, 0.f, 0.f, 0.f};
  for (int c = 0; c < NCH; ++c) {
    *(f32x4*)(carry + (size_t)c * NCHAIN + ch0) = cs;
    f32x4 sm = *(const f32x4*)(csum + (size_t)c * NCHAIN + ch0);
    cs = lamC * cs + sm;
  }
}

// ---- fused: y = q*(st + lam^{tl+1}*carry); LayerNorm(D); * silu(g); -> bf16 ----
__global__ __launch_bounds__(256) void fuse_ln(const __bf16* __restrict__ qb,
                                               const float* __restrict__ st,
                                               const float* __restrict__ carry,
                                               const __bf16* __restrict__ gb,
                                               const float* __restrict__ decay,
                                               const float* __restrict__ ln_g,
                                               const float* __restrict__ ln_b,
                                               __bf16* __restrict__ y2) {
  const int row = blockIdx.x;                 // b*L + l
  const int l = row & (LSEQ - 1), b = row >> 12;
  const int c = l >> 5, tl = l & (CHUNK - 1);
  const int d0 = threadIdx.x * 4;
  const float lam = decay[((d0 >> 6) << 1) + 1];
  const float p = __powf(lam, (float)(tl + 1));
  const size_t base = (size_t)row * DM + d0;

  f32x4 s4 = *(const f32x4*)(st + base);
  f32x4 cr = *(const f32x4*)(carry + (size_t)c * NCHAIN + b * DM + d0);
  bf16x4 q4 = *(const bf16x4*)(qb + base);

  f32x4 y;
  float sum = 0.f, ssq = 0.f;
#pragma unroll
  for (int i = 0; i < 4; ++i) {
    float yy = (float)q4[i] * (s4[i] + p * cr[i]);
    y[i] = yy;
    sum += yy;
    ssq += yy * yy;
  }
#pragma unroll
  for (int o = 32; o > 0; o >>= 1) {
    sum += __shfl_xor(sum, o);
    ssq += __shfl_xor(ssq, o);
  }
  __shared__ float sb[8];
  if ((threadIdx.x & 63) == 0) {
    sb[threadIdx.x >> 6] = sum;
    sb[4 + (threadIdx.x >> 6)] = ssq;
  }
  __syncthreads();
  sum = sb[0] + sb[1] + sb[2] + sb[3];
  ssq = sb[4] + sb[5] + sb[6] + sb[7];

  const float mu = sum * (1.0f / DM);
  const float var = ssq * (1.0f / DM) - mu * mu;
  const float rstd = rsqrtf(fmaxf(var, 0.0f) + 1e-5f);

  bf16x4 g4 = *(const bf16x4*)(gb + base);
  f32x4 lg = *(const f32x4*)(ln_g + d0);
  f32x4 lb = *(const f32x4*)(ln_b + d0);
  bf16x4 o4;
#pragma unroll
  for (int i = 0; i < 4; ++i) {
    float gv = (float)g4[i];
    float gate = gv / (1.0f + __expf(-gv));
    float val = fmaf((y[i] - mu) * rstd, lg[i], lb[i]) * gate;
    o4[i] = (__bf16)val;
  }
  *(bf16x4*)(y2 + base) = o4;
}

extern "C" void kernel_launch(void* const* d_in, const int* in_sizes, int n_in,
                              void* d_out, int out_size, void* d_ws, size_t ws_size,
                              hipStream_t stream) {
  const float* x     = (const float*)d_in[0];
  // d_in[1]=sin, d_in[2]=cos (unused by reference)
  const float* decay = (const float*)d_in[3];
  const float* Wq    = (const float*)d_in[4];
  const float* Wv    = (const float*)d_in[5];
  const float* Wo    = (const float*)d_in[6];
  const float* Wg    = (const float*)d_in[7];
  const float* lng   = (const float*)d_in[8];
  const float* lnb   = (const float*)d_in[9];
  float* out = (float*)d_out;

  char* ws = (char*)d_ws;
  size_t off = 0;
  auto alloc = [&](size_t bytes) -> void* {
    void* p = ws + off;
    off += (bytes + 255) & ~(size_t)255;
    return p;
  };
  __bf16* xb   = (__bf16*)alloc(MD * 2);        // x in bf16
  __bf16* wqvg = (__bf16*)alloc(3 * DD * 2);    // Wq|Wv|Wg in bf16
  __bf16* wob  = (__bf16*)alloc(DD * 2);        // Wo in bf16
  __bf16* qvg  = (__bf16*)alloc(3 * MD * 2);    // q|v|g
  __bf16* y2b  = (__bf16*)alloc(MD * 2);        // post-LN*gate in bf16
  float*  st   = (float*)alloc(MD * 4);         // local scan states
  float*  csum = (float*)alloc((size_t)NCH * NCHAIN * 4);
  float*  cry  = (float*)alloc((size_t)NCH * NCHAIN * 4);

  // converts
  cvt_bf16<<<(int)(MD / 1024), 256, 0, stream>>>(x, xb);
  cvt_bf16<<<(int)(DD / 1024), 256, 0, stream>>>(Wq, wqvg);
  cvt_bf16<<<(int)(DD / 1024), 256, 0, stream>>>(Wv, wqvg + DD);
  cvt_bf16<<<(int)(DD / 1024), 256, 0, stream>>>(Wg, wqvg + 2 * DD);
  cvt_bf16<<<(int)(DD / 1024), 256, 0, stream>>>(Wo, wob);

  // q,v,g projections (one launch, z selects weight/out)
  gemm_nt<__bf16><<<dim3(DM / 128, MROWS / 128, 3), 256, 0, stream>>>(xb, wqvg, qvg);

  // retention scan
  scan1<<<(BATCH * NCH * (DM / 4)) / 256, 256, 0, stream>>>(qvg + MD, st, csum, decay);
  scan2<<<(NCHAIN / 4) / 256, 256, 0, stream>>>(csum, cry, decay);

  // fused elementwise + LN + gate
  fuse_ln<<<MROWS, 256, 0, stream>>>(qvg, st, cry, qvg + 2 * MD, decay, lng, lnb, y2b);

  // output projection -> f32 out
  gemm_nt<float><<<dim3(DM / 128, MROWS / 128, 1), 256, 0, stream>>>(y2b, wob, out);
}

// Round 2
// 235.429 us; speedup vs baseline: 1.2454x; 1.2454x over previous
//
#include <hip/hip_runtime.h>

// ---- problem constants ----
#define DM    1024
#define LSEQ  4096
#define BATCH 4
#define MROWS (BATCH * LSEQ)           // 16384 rows
#define MD    ((size_t)MROWS * DM)     // 16,777,216 elems
#define DD    ((size_t)DM * DM)        // 1,048,576 elems
#define CHUNK 32
#define NCH   (LSEQ / CHUNK)           // 128 chunks
#define NCHAIN (BATCH * DM)            // 4096 scan chains

typedef __attribute__((ext_vector_type(4))) float  f32x4;
typedef __attribute__((ext_vector_type(8))) __bf16 bf16x8;
typedef __attribute__((ext_vector_type(4))) __bf16 bf16x4;

__device__ __forceinline__ void gload_lds16(const void* g, void* l) {
  __builtin_amdgcn_global_load_lds(
      (const __attribute__((address_space(1))) void*)g,
      (__attribute__((address_space(3))) void*)l, 16, 0, 0);
}

// ---- fp32 -> bf16 convert ----
__global__ __launch_bounds__(256) void cvt_bf16(const float* __restrict__ in,
                                                __bf16* __restrict__ out) {
  size_t i = ((size_t)blockIdx.x * 256 + threadIdx.x) * 4;
  f32x4 f = *(const f32x4*)(in + i);
  bf16x4 o;
#pragma unroll
  for (int j = 0; j < 4; ++j) o[j] = (__bf16)f[j];
  *(bf16x4*)(out + i) = o;
}

// ======================= 256x256 8-phase bf16 NT GEMM =======================
// C[m][n] = sum_k A[m][k] * W[n][k].  M=16384, N=K=1024.
// 8 waves (2Mx4N), BK=64, LDS 128KiB double-buffered, counted vmcnt,
// XOR-swizzled LDS (byte ^= (row&7)<<4 — conflict-free for 128B rows),
// applied as inverse-swizzled global source + swizzled ds_read (gload_lds
// writes linearly). blockIdx.z selects (W, C) pair.

// swizzle on flat tile byte offset: rows are 128B; row bits = [7..9]
__device__ __forceinline__ int swz(int b) { return b ^ ((b >> 3) & 0x70); }

__device__ __forceinline__ bf16x8 ldf(const char* tile, int row, int k) {
  int lin = (row << 7) + (k << 1);
  return *(const bf16x8*)(tile + swz(lin));
}

// stage one 128-row half-tile (2 issues x 512 thr x 16B). dest linear,
// source inverse-permuted so swizzled reads see the right data.
__device__ __forceinline__ void stage_half(const __bf16* srcRow0, char* tile,
                                           int halfOff, int k0, int t) {
#pragma unroll
  for (int is = 0; is < 2; ++is) {
    int d = halfOff + is * 8192 + t * 16;
    int l = swz(d);
    int row = l >> 7, cb = l & 127;
    gload_lds16((const char*)srcRow0 + (size_t)row * (DM * 2) + k0 * 2 + cb,
                tile + d);
  }
}

template <typename OutT>
__global__ __launch_bounds__(512, 2) void gemm_nt(const __bf16* __restrict__ A,
                                                  const __bf16* __restrict__ Wb,
                                                  OutT* __restrict__ Cb) {
  constexpr int K = DM, N = DM, NT = K / 64;
  __shared__ __attribute__((aligned(128))) char lds[131072];

  const __bf16* Wp = Wb + (size_t)blockIdx.z * DD;
  OutT* Cp = Cb + (size_t)blockIdx.z * MD;

  // bijective XCD swizzle: nwg = 4*64 = 256, divisible by 8
  const int orig = blockIdx.y * 4 + blockIdx.x;
  const int sid = (orig & 7) * 32 + (orig >> 3);
  const int bx = sid & 3, by = sid >> 2;
  const int m0 = by * 256, n0 = bx * 256;

  const int t = threadIdx.x, lane = t & 63, wv = t >> 6;
  const int wr = wv >> 2, wc = wv & 3;          // 2 x 4 waves
  const int lrow = lane & 15, lk8 = (lane >> 4) * 8;

  const __bf16* Abase = A + (size_t)m0 * K;
  const __bf16* Bbase = Wp + (size_t)n0 * K;

  f32x4 acc[8][4] = {};
  bf16x8 a[4][2];        // current A mh-half frags
  bf16x8 bq[2][2][2];    // B frags [nh][nf][ks]

  char* buf0 = lds;             // A at +0, B at +32768 within each buf
  char* buf1 = lds + 65536;

  // prologue: kt0 {A0,A1,B0,B1} + kt1.{B0,A0}; wait first 4 halves
  stage_half(Abase, buf0,         0,  0, t);
  stage_half(Abase, buf0,     16384,  0, t);
  stage_half(Bbase, buf0 + 32768, 0,  0, t);
  stage_half(Bbase, buf0 + 32768, 16384, 0, t);
  stage_half(Bbase, buf1 + 32768, 0, 64, t);
  stage_half(Abase, buf1,         0, 64, t);
  asm volatile("s_waitcnt vmcnt(4)" ::: "memory");
  __builtin_amdgcn_s_barrier();
  __builtin_amdgcn_sched_barrier(0);

#define LDA_(mh)                                                        \
  _Pragma("unroll") for (int mf = 0; mf < 4; ++mf)                      \
  _Pragma("unroll") for (int ks = 0; ks < 2; ++ks)                      \
    a[mf][ks] = ldf(At, wr * 128 + (mh) * 64 + mf * 16 + lrow, ks * 32 + lk8);
#define LDB_(nh)                                                        \
  _Pragma("unroll") for (int nf = 0; nf < 2; ++nf)                      \
  _Pragma("unroll") for (int ks = 0; ks < 2; ++ks)                      \
    bq[nh][nf][ks] = ldf(Bt, wc * 64 + (nh) * 32 + nf * 16 + lrow, ks * 32 + lk8);
#define MFMA16_(mh, nh)                                                 \
  __builtin_amdgcn_s_setprio(1);                                        \
  _Pragma("unroll") for (int mf = 0; mf < 4; ++mf)                      \
  _Pragma("unroll") for (int nf = 0; nf < 2; ++nf)                      \
  _Pragma("unroll") for (int ks = 0; ks < 2; ++ks)                      \
    acc[(mh) * 4 + mf][(nh) * 2 + nf] = __builtin_amdgcn_mfma_f32_16x16x32_bf16( \
        a[mf][ks], bq[nh][nf][ks], acc[(mh) * 4 + mf][(nh) * 2 + nf], 0, 0, 0); \
  __builtin_amdgcn_s_setprio(0);
#define SYNC_IN_                                                        \
  __builtin_amdgcn_s_barrier();                                         \
  asm volatile("s_waitcnt lgkmcnt(0)" ::: "memory");                    \
  __builtin_amdgcn_sched_barrier(0);
#define SYNC_OUT_                                                       \
  __builtin_amdgcn_s_barrier();                                         \
  __builtin_amdgcn_sched_barrier(0);

#pragma unroll 1
  for (int kt = 0; kt < NT; ++kt) {
    char* bufc = lds + (kt & 1) * 65536;
    char* bufn = lds + (((kt & 1) ^ 1)) * 65536;
    const char* At = bufc;
    const char* Bt = bufc + 32768;
    const int k1 = (kt + 1) << 6, k2 = (kt + 2) << 6;
    const bool s1 = (kt + 1 < NT), s2 = (kt + 2 < NT);

    // P1 (mh0,nh0): ds A0(8)+B0(4); stage kt+1.B1
    LDA_(0); LDB_(0);
    if (s1) stage_half(Bbase, bufn + 32768, 16384, k1, t);
    SYNC_IN_; MFMA16_(0, 0); SYNC_OUT_;

    // P2 (mh0,nh1): ds B1(4); stage kt+1.A1
    LDB_(1);
    if (s1) stage_half(Abase, bufn, 16384, k1, t);
    SYNC_IN_; MFMA16_(0, 1); SYNC_OUT_;

    // P3 (mh1,nh0): ds A1(8); stage kt+2.B0 (B region of bufc free after P2)
    LDA_(1);
    if (s2) stage_half(Bbase, bufc + 32768, 0, k2, t);
    SYNC_IN_; MFMA16_(1, 0); SYNC_OUT_;

    // P4 (mh1,nh1): no ds; stage kt+2.A0 (A region free after P3)
    if (s2) stage_half(Abase, bufc, 0, k2, t);
    __builtin_amdgcn_s_barrier();
    __builtin_amdgcn_sched_barrier(0);
    MFMA16_(1, 1);
    // K-tile boundary: counted vmcnt — kt+1 resident, kt+2 halves in flight
    if (s2) { asm volatile("s_waitcnt vmcnt(4)" ::: "memory"); }
    else    { asm volatile("s_waitcnt vmcnt(0)" ::: "memory"); }
    __builtin_amdgcn_s_barrier();
    __builtin_amdgcn_sched_barrier(0);
  }
#undef LDA_
#undef LDB_
#undef MFMA16_
#undef SYNC_IN_
#undef SYNC_OUT_

  // epilogue: C/D layout col=lane&15, row=(lane>>4)*4+j
#pragma unroll
  for (int mi = 0; mi < 8; ++mi) {
    int r0 = m0 + wr * 128 + mi * 16 + (lane >> 4) * 4;
#pragma unroll
    for (int ni = 0; ni < 4; ++ni) {
      int c0 = n0 + wc * 64 + ni * 16 + (lane & 15);
#pragma unroll
      for (int j = 0; j < 4; ++j) {
        float v = acc[mi][ni][j];
        if constexpr (__is_same(OutT, float))
          Cp[(size_t)(r0 + j) * N + c0] = v;
        else
          Cp[(size_t)(r0 + j) * N + c0] = (__bf16)v;
      }
    }
  }
}

// ---- retention scan pass1 ----
__global__ __launch_bounds__(256) void scan1(const __bf16* __restrict__ v,
                                             float* __restrict__ st,
                                             float* __restrict__ csum,
                                             const float* __restrict__ decay) {
  int tid = blockIdx.x * 256 + threadIdx.x;
  int dg = tid & 255;
  int b  = (tid >> 8) & 3;
  int c  = tid >> 10;
  int d0 = dg * 4;
  float lam = decay[((d0 >> 6) << 1) + 1];
  f32x4 s = {0.f, 0.f, 0.f, 0.f};
  size_t base = ((size_t)b * LSEQ + (size_t)c * CHUNK) * DM + d0;
  for (int t = 0; t < CHUNK; ++t) {
    bf16x4 vv = *(const bf16x4*)(v + base);
    f32x4 vf = {(float)vv[0], (float)vv[1], (float)vv[2], (float)vv[3]};
    s = lam * s + vf;
    *(f32x4*)(st + base) = s;
    base += DM;
  }
  *(f32x4*)(csum + (size_t)c * NCHAIN + b * DM + d0) = s;
}

// ---- pass2: carry-in per chunk ----
__global__ __launch_bounds__(256) void scan2(const float* __restrict__ csum,
                                             float* __restrict__ carry,
                                             const float* __restrict__ decay) {
  int i = blockIdx.x * 256 + threadIdx.x;
  int ch0 = i * 4;
  int d0 = ch0 & (DM - 1);
  float lam = decay[((d0 >> 6) << 1) + 1];
  float l2 = lam * lam, l4 = l2 * l2, l8 = l4 * l4, l16 = l8 * l8;
  float lamC = l16 * l16;
  f32x4 cs = {0.f, 0.f, 0.f, 0.f};
  for (int c = 0; c < NCH; ++c) {
    *(f32x4*)(carry + (size_t)c * NCHAIN + ch0) = cs;
    f32x4 sm = *(const f32x4*)(csum + (size_t)c * NCHAIN + ch0);
    cs = lamC * cs + sm;
  }
}

// ---- fused: y = q*(st + lam^{tl+1}*carry); LN; *silu(g); -> bf16 ----
__global__ __launch_bounds__(256) void fuse_ln(const __bf16* __restrict__ qb,
                                               const float* __restrict__ st,
                                               const float* __restrict__ carry,
                                               const __bf16* __restrict__ gb,
                                               const float* __restrict__ decay,
                                               const float* __restrict__ ln_g,
                                               const float* __restrict__ ln_b,
                                               __bf16* __restrict__ y2) {
  const int row = blockIdx.x;
  const int l = row & (LSEQ - 1), b = row >> 12;
  const int c = l >> 5, tl = l & (CHUNK - 1);
  const int d0 = threadIdx.x * 4;
  const float lam = decay[((d0 >> 6) << 1) + 1];
  const float p = __powf(lam, (float)(tl + 1));
  const size_t base = (size_t)row * DM + d0;

  f32x4 s4 = *(const f32x4*)(st + base);
  f32x4 cr = *(const f32x4*)(carry + (size_t)c * NCHAIN + b * DM + d0);
  bf16x4 q4 = *(const bf16x4*)(qb + base);

  f32x4 y;
  float sum = 0.f, ssq = 0.f;
#pragma unroll
  for (int i = 0; i < 4; ++i) {
    float yy = (float)q4[i] * (s4[i] + p * cr[i]);
    y[i] = yy;
    sum += yy;
    ssq += yy * yy;
  }
#pragma unroll
  for (int o = 32; o > 0; o >>= 1) {
    sum += __shfl_xor(sum, o);
    ssq += __shfl_xor(ssq, o);
  }
  __shared__ float sb[8];
  if ((threadIdx.x & 63) == 0) {
    sb[threadIdx.x >> 6] = sum;
    sb[4 + (threadIdx.x >> 6)] = ssq;
  }
  __syncthreads();
  sum = sb[0] + sb[1] + sb[2] + sb[3];
  ssq = sb[4] + sb[5] + sb[6] + sb[7];

  const float mu = sum * (1.0f / DM);
  const float var = ssq * (1.0f / DM) - mu * mu;
  const float rstd = rsqrtf(fmaxf(var, 0.0f) + 1e-5f);

  bf16x4 g4 = *(const bf16x4*)(gb + base);
  f32x4 lg = *(const f32x4*)(ln_g + d0);
  f32x4 lb = *(const f32x4*)(ln_b + d0);
  bf16x4 o4;
#pragma unroll
  for (int i = 0; i < 4; ++i) {
    float gv = (float)g4[i];
    float gate = gv / (1.0f + __expf(-gv));
    float val = fmaf((y[i] - mu) * rstd, lg[i], lb[i]) * gate;
    o4[i] = (__bf16)val;
  }
  *(bf16x4*)(y2 + base) = o4;
}

extern "C" void kernel_launch(void* const* d_in, const int* in_sizes, int n_in,
                              void* d_out, int out_size, void* d_ws, size_t ws_size,
                              hipStream_t stream) {
  const float* x     = (const float*)d_in[0];
  const float* decay = (const float*)d_in[3];
  const float* Wq    = (const float*)d_in[4];
  const float* Wv    = (const float*)d_in[5];
  const float* Wo    = (const float*)d_in[6];
  const float* Wg    = (const float*)d_in[7];
  const float* lng   = (const float*)d_in[8];
  const float* lnb   = (const float*)d_in[9];
  float* out = (float*)d_out;

  char* ws = (char*)d_ws;
  size_t off = 0;
  auto alloc = [&](size_t bytes) -> void* {
    void* p = ws + off;
    off += (bytes + 255) & ~(size_t)255;
    return p;
  };
  __bf16* xb   = (__bf16*)alloc(MD * 2);
  __bf16* wqvg = (__bf16*)alloc(3 * DD * 2);
  __bf16* wob  = (__bf16*)alloc(DD * 2);
  __bf16* qvg  = (__bf16*)alloc(3 * MD * 2);
  __bf16* y2b  = (__bf16*)alloc(MD * 2);
  float*  st   = (float*)alloc(MD * 4);
  float*  csum = (float*)alloc((size_t)NCH * NCHAIN * 4);
  float*  cry  = (float*)alloc((size_t)NCH * NCHAIN * 4);

  cvt_bf16<<<(int)(MD / 1024), 256, 0, stream>>>(x, xb);
  cvt_bf16<<<(int)(DD / 1024), 256, 0, stream>>>(Wq, wqvg);
  cvt_bf16<<<(int)(DD / 1024), 256, 0, stream>>>(Wv, wqvg + DD);
  cvt_bf16<<<(int)(DD / 1024), 256, 0, stream>>>(Wg, wqvg + 2 * DD);
  cvt_bf16<<<(int)(DD / 1024), 256, 0, stream>>>(Wo, wob);

  gemm_nt<__bf16><<<dim3(4, MROWS / 256, 3), 512, 0, stream>>>(xb, wqvg, qvg);

  scan1<<<(BATCH * NCH * (DM / 4)) / 256, 256, 0, stream>>>(qvg + MD, st, csum, decay);
  scan2<<<(NCHAIN / 4) / 256, 256, 0, stream>>>(csum, cry, decay);

  fuse_ln<<<MROWS, 256, 0, stream>>>(qvg, st, cry, qvg + 2 * MD, decay, lng, lnb, y2b);

  gemm_nt<float><<<dim3(4, MROWS / 256, 1), 512, 0, stream>>>(y2b, wob, out);
}

// Round 3
// 215.460 us; speedup vs baseline: 1.3608x; 1.0927x over previous
//
#include <hip/hip_runtime.h>

// ---- problem constants ----
#define DM    1024
#define LSEQ  4096
#define BATCH 4
#define MROWS (BATCH * LSEQ)           // 16384 rows
#define MD    ((size_t)MROWS * DM)     // 16,777,216 elems
#define DD    ((size_t)DM * DM)        // 1,048,576 elems
#define CHUNK 32
#define NCH   (LSEQ / CHUNK)           // 128 chunks
#define NCHAIN (BATCH * DM)            // 4096 scan chains

typedef __attribute__((ext_vector_type(4))) float  f32x4;
typedef __attribute__((ext_vector_type(8))) __bf16 bf16x8;
typedef __attribute__((ext_vector_type(4))) __bf16 bf16x4;

__device__ __forceinline__ void gload_lds16(const void* g, void* l) {
  __builtin_amdgcn_global_load_lds(
      (const __attribute__((address_space(1))) void*)g,
      (__attribute__((address_space(3))) void*)l, 16, 0, 0);
}

// ---- fp32 -> bf16 converts ----
__global__ __launch_bounds__(256) void cvt_bf16(const float* __restrict__ in,
                                                __bf16* __restrict__ out) {
  size_t i = ((size_t)blockIdx.x * 256 + threadIdx.x) * 4;
  f32x4 f = *(const f32x4*)(in + i);
  bf16x4 o;
#pragma unroll
  for (int j = 0; j < 4; ++j) o[j] = (__bf16)f[j];
  *(bf16x4*)(out + i) = o;
}

__global__ __launch_bounds__(256) void cvt_w(const float* __restrict__ s0,
                                             const float* __restrict__ s1,
                                             const float* __restrict__ s2,
                                             const float* __restrict__ s3,
                                             __bf16* __restrict__ dst) {
  const float* sp = (blockIdx.z == 0) ? s0 : (blockIdx.z == 1) ? s1
                  : (blockIdx.z == 2) ? s2 : s3;
  size_t i = ((size_t)blockIdx.x * 256 + threadIdx.x) * 4;
  f32x4 f = *(const f32x4*)(sp + i);
  bf16x4 o;
#pragma unroll
  for (int j = 0; j < 4; ++j) o[j] = (__bf16)f[j];
  *(bf16x4*)(dst + (size_t)blockIdx.z * DD + i) = o;
}

// ======================= 256x256 8-phase bf16 NT GEMM =======================
// C[m][n] = sum_k A[m][k] * W[n][k].  M=16384, N=K=1024.
// 8 waves (2Mx4N), BK=64, 128KiB LDS double-buffered.
// LDS row order remapped so half-tiles align with phase readers:
//   A: lds_r = mh*128 + wr*64 + r64   (half h = mh stripe pair)
//   B: lds_r = nh*128 + wc*32 + r32   (half h = nh stripe quad)
// Phase readers: P1:{A0,B0} P2:{B1} P3:{A1} P4:{-}. Iteration kt stages kt+2
// into the CURRENT buffer's dead regions (P2: A0+B0, P3: B1, P4: A1) giving
// ~7-phase (:>1400cy) prefetch lead; per-phase counted vmcnt never stalls.

__device__ __forceinline__ int swz(int b) { return b ^ ((b >> 3) & 0x70); }

__device__ __forceinline__ bf16x8 ldf(const char* tile, int row, int k) {
  int lin = (row << 7) + (k << 1);
  return *(const bf16x8*)(tile + swz(lin));
}

// stage one 128-lds-row half (2 issues x 512 thr x 16B), dest linear,
// source inverse-permuted through swz + the half row-remap.
__device__ __forceinline__ void stageA_half(const __bf16* Abase, char* tileA,
                                            int h, int k0, int t) {
#pragma unroll
  for (int is = 0; is < 2; ++is) {
    int d = h * 16384 + is * 8192 + t * 16;
    int l = swz(d);
    int lds_r = l >> 7, cb = l & 127;
    int g = ((lds_r >> 6) & 1) * 128 + h * 64 + (lds_r & 63);   // wr*128+h*64+r64
    gload_lds16((const char*)Abase + (size_t)g * (DM * 2) + k0 * 2 + cb, tileA + d);
  }
}
__device__ __forceinline__ void stageB_half(const __bf16* Bbase, char* tileB,
                                            int h, int k0, int t) {
#pragma unroll
  for (int is = 0; is < 2; ++is) {
    int d = h * 16384 + is * 8192 + t * 16;
    int l = swz(d);
    int lds_r = l >> 7, cb = l & 127;
    int g = ((lds_r >> 5) & 3) * 64 + h * 32 + (lds_r & 31);    // wc*64+h*32+r32
    gload_lds16((const char*)Bbase + (size_t)g * (DM * 2) + k0 * 2 + cb, tileB + d);
  }
}

template <typename OutT>
__global__ __launch_bounds__(512, 2) void gemm_nt(const __bf16* __restrict__ A,
                                                  const __bf16* __restrict__ Wb,
                                                  OutT* __restrict__ Cb) {
  constexpr int K = DM, N = DM, NT = K / 64;
  __shared__ __attribute__((aligned(128))) char lds[131072];

  const __bf16* Wp = Wb + (size_t)blockIdx.z * DD;
  OutT* Cp = Cb + (size_t)blockIdx.z * MD;

  // bijective XCD swizzle: nwg = 4*64 = 256, divisible by 8
  const int orig = blockIdx.y * 4 + blockIdx.x;
  const int sid = (orig & 7) * 32 + (orig >> 3);
  const int bx = sid & 3, by = sid >> 2;
  const int m0 = by * 256, n0 = bx * 256;

  const int t = threadIdx.x, lane = t & 63, wv = t >> 6;
  const int wr = wv >> 2, wc = wv & 3;          // 2 x 4 waves
  const int lrow = lane & 15, lk8 = (lane >> 4) * 8;

  const __bf16* Abase = A + (size_t)m0 * K;
  const __bf16* Bbase = Wp + (size_t)n0 * K;

  f32x4 acc[8][4] = {};
  bf16x8 a[4][2];        // current A mh-half frags
  bf16x8 bq[2][2][2];    // B frags [nh][nf][ks]

  char* buf0 = lds;             // A at +0, B at +32768 within each buf
  char* buf1 = lds + 65536;

  // prologue: kt0 halves {A0,B0,B1,A1} then kt1 same order (16 insts)
  stageA_half(Abase, buf0,         0, 0, t);
  stageB_half(Bbase, buf0 + 32768, 0, 0, t);
  stageB_half(Bbase, buf0 + 32768, 1, 0, t);
  stageA_half(Abase, buf0,         1, 0, t);
  stageA_half(Abase, buf1,         0, 64, t);
  stageB_half(Bbase, buf1 + 32768, 0, 64, t);
  stageB_half(Bbase, buf1 + 32768, 1, 64, t);
  stageA_half(Abase, buf1,         1, 64, t);
  asm volatile("s_waitcnt vmcnt(12)" ::: "memory");   // A0(0),B0(0) resident
  __builtin_amdgcn_s_barrier();
  __builtin_amdgcn_sched_barrier(0);

#define LDA_(mh)                                                        \
  _Pragma("unroll") for (int mf = 0; mf < 4; ++mf)                      \
  _Pragma("unroll") for (int ks = 0; ks < 2; ++ks)                      \
    a[mf][ks] = ldf(At, (mh) * 128 + wr * 64 + mf * 16 + lrow, ks * 32 + lk8);
#define LDB_(nh)                                                        \
  _Pragma("unroll") for (int nf = 0; nf < 2; ++nf)                      \
  _Pragma("unroll") for (int ks = 0; ks < 2; ++ks)                      \
    bq[nh][nf][ks] = ldf(Bt, (nh) * 128 + wc * 32 + nf * 16 + lrow, ks * 32 + lk8);
#define MFMA16_(mh, nh)                                                 \
  __builtin_amdgcn_s_setprio(1);                                        \
  _Pragma("unroll") for (int mf = 0; mf < 4; ++mf)                      \
  _Pragma("unroll") for (int nf = 0; nf < 2; ++nf)                      \
  _Pragma("unroll") for (int ks = 0; ks < 2; ++ks)                      \
    acc[(mh) * 4 + mf][(nh) * 2 + nf] = __builtin_amdgcn_mfma_f32_16x16x32_bf16( \
        a[mf][ks], bq[nh][nf][ks], acc[(mh) * 4 + mf][(nh) * 2 + nf], 0, 0, 0); \
  __builtin_amdgcn_s_setprio(0);
#define BAR_LGKM_                                                       \
  __builtin_amdgcn_s_barrier();                                         \
  asm volatile("s_waitcnt lgkmcnt(0)" ::: "memory");                    \
  __builtin_amdgcn_sched_barrier(0);
#define VM_BAR_(n)                                                      \
  asm volatile("s_waitcnt vmcnt(" #n ")" ::: "memory");                 \
  __builtin_amdgcn_s_barrier();                                         \
  __builtin_amdgcn_sched_barrier(0);

#pragma unroll 1
  for (int kt = 0; kt < NT; ++kt) {
    char* bufc = lds + (kt & 1) * 65536;
    const char* At = bufc;
    const char* Bt = bufc + 32768;
    const int k2 = ((kt + 2) & (NT - 1)) << 6;   // wrap: dummy re-stage at tail

    // P1: ds A0+B0 (12 reads); no stage
    LDA_(0); LDB_(0);
    BAR_LGKM_; MFMA16_(0, 0);
    VM_BAR_(10);                                  // B1(kt) resident

    // P2: ds B1; stage kt+2 {A0,B0} into dead regions of bufc
    LDB_(1);
    stageA_half(Abase, bufc,         0, k2, t);
    stageB_half(Bbase, bufc + 32768, 0, k2, t);
    BAR_LGKM_; MFMA16_(0, 1);
    VM_BAR_(12);                                  // A1(kt) resident

    // P3: ds A1; stage kt+2 B1
    LDA_(1);
    stageB_half(Bbase, bufc + 32768, 1, k2, t);
    BAR_LGKM_; MFMA16_(1, 0);
    __builtin_amdgcn_s_barrier();
    __builtin_amdgcn_sched_barrier(0);

    // P4: no ds; stage kt+2 A1; regs-only MFMA
    stageA_half(Abase, bufc, 1, k2, t);
    MFMA16_(1, 1);
    VM_BAR_(12);                                  // A0,B0(kt+1) resident
  }
#undef LDA_
#undef LDB_
#undef MFMA16_
#undef BAR_LGKM_
#undef VM_BAR_

  // epilogue: C/D layout col=lane&15, row=(lane>>4)*4+j
#pragma unroll
  for (int mi = 0; mi < 8; ++mi) {
    int r0 = m0 + wr * 128 + (mi >> 2) * 64 + (mi & 3) * 16 + (lane >> 4) * 4;
#pragma unroll
    for (int ni = 0; ni < 4; ++ni) {
      int c0 = n0 + wc * 64 + (ni >> 1) * 32 + (ni & 1) * 16 + (lane & 15);
#pragma unroll
      for (int j = 0; j < 4; ++j) {
        float v = acc[mi][ni][j];
        if constexpr (__is_same(OutT, float))
          Cp[(size_t)(r0 + j) * N + c0] = v;
        else
          Cp[(size_t)(r0 + j) * N + c0] = (__bf16)v;
      }
    }
  }
}

// ---- chunk sums: csum[c][chain] = sum_t lam^(31-t) v_t over chunk c ----
__global__ __launch_bounds__(256) void scan_sum(const __bf16* __restrict__ v,
                                                float* __restrict__ csum,
                                                const float* __restrict__ decay) {
  int tid = blockIdx.x * 256 + threadIdx.x;
  int dg = tid & 255;
  int b  = (tid >> 8) & 3;
  int c  = tid >> 10;
  int d0 = dg * 4;
  float lam = decay[((d0 >> 6) << 1) + 1];
  f32x4 s = {0.f, 0.f, 0.f, 0.f};
  size_t base = ((size_t)b * LSEQ + (size_t)c * CHUNK) * DM + d0;
  for (int t = 0; t < CHUNK; ++t) {
    bf16x4 vv = *(const bf16x4*)(v + base);
    f32x4 vf = {(float)vv[0], (float)vv[1], (float)vv[2], (float)vv[3]};
    s = lam * s + vf;
    base += DM;
  }
  *(f32x4*)(csum + (size_t)c * NCHAIN + b * DM + d0) = s;
}

// ---- pass2: carry[c][chain] = full state entering chunk c ----
__global__ __launch_bounds__(256) void scan2(const float* __restrict__ csum,
                                             float* __restrict__ carry,
                                             const float* __restrict__ decay) {
  int i = blockIdx.x * 256 + threadIdx.x;
  int ch0 = i * 4;
  int d0 = ch0 & (DM - 1);
  float lam = decay[((d0 >> 6) << 1) + 1];
  float l2 = lam * lam, l4 = l2 * l2, l8 = l4 * l4, l16 = l8 * l8;
  float lamC = l16 * l16;
  f32x4 cs = {0.f, 0.f, 0.f, 0.f};
  for (int c = 0; c < NCH; ++c) {
    *(f32x4*)(carry + (size_t)c * NCHAIN + ch0) = cs;
    f32x4 sm = *(const f32x4*)(csum + (size_t)c * NCHAIN + ch0);
    cs = lamC * cs + sm;
  }
}

// ---- fused per-chunk: exact scan (carry-seeded) + y=q*s + LN + silu gate ----
// one block per (b, chunk): 256 thr, thread owns 4 channels x 32 rows.
__global__ __launch_bounds__(256) void fuse_chunk(
    const __bf16* __restrict__ qb, const __bf16* __restrict__ vb,
    const __bf16* __restrict__ gb, const float* __restrict__ carry,
    const float* __restrict__ decay, const float* __restrict__ ln_g,
    const float* __restrict__ ln_b, __bf16* __restrict__ y2) {
  const int blk = blockIdx.x;
  const int b = blk >> 7, c = blk & 127;
  const int t = threadIdx.x, lane = t & 63, wv = t >> 6;
  const int d0 = t * 4;
  const float lam = decay[((d0 >> 6) << 1) + 1];
  f32x4 s = *(const f32x4*)(carry + (size_t)c * NCHAIN + b * DM + d0);
  const size_t base0 = ((size_t)b * LSEQ + (size_t)c * CHUNK) * DM + d0;

  __shared__ float sbs[2][32][4];
  __shared__ float stats[32][2];

  f32x4 y[32];
#pragma unroll
  for (int r = 0; r < 32; ++r) {
    size_t base = base0 + (size_t)r * DM;
    bf16x4 v4 = *(const bf16x4*)(vb + base);
    bf16x4 q4 = *(const bf16x4*)(qb + base);
    f32x4 vf = {(float)v4[0], (float)v4[1], (float)v4[2], (float)v4[3]};
    s = lam * s + vf;
    f32x4 yy;
    float su = 0.f, sq = 0.f;
#pragma unroll
    for (int i = 0; i < 4; ++i) {
      float val = (float)q4[i] * s[i];
      yy[i] = val; su += val; sq += val * val;
    }
    y[r] = yy;
#pragma unroll
    for (int o = 32; o > 0; o >>= 1) {
      su += __shfl_xor(su, o);
      sq += __shfl_xor(sq, o);
    }
    if (lane == 0) { sbs[0][r][wv] = su; sbs[1][r][wv] = sq; }
  }
  __syncthreads();
  if (t < 32) {
    float su = sbs[0][t][0] + sbs[0][t][1] + sbs[0][t][2] + sbs[0][t][3];
    float sq = sbs[1][t][0] + sbs[1][t][1] + sbs[1][t][2] + sbs[1][t][3];
    float mu = su * (1.0f / DM);
    float var = sq * (1.0f / DM) - mu * mu;
    stats[t][0] = mu;
    stats[t][1] = rsqrtf(fmaxf(var, 0.0f) + 1e-5f);
  }
  __syncthreads();

  f32x4 lg = *(const f32x4*)(ln_g + d0);
  f32x4 lb = *(const f32x4*)(ln_b + d0);
#pragma unroll
  for (int r = 0; r < 32; ++r) {
    size_t base = base0 + (size_t)r * DM;
    bf16x4 g4 = *(const bf16x4*)(gb + base);
    const float mu = stats[r][0], rstd = stats[r][1];
    bf16x4 o4;
#pragma unroll
    for (int i = 0; i < 4; ++i) {
      float gv = (float)g4[i];
      float gate = gv / (1.0f + __expf(-gv));
      o4[i] = (__bf16)(fmaf((y[r][i] - mu) * rstd, lg[i], lb[i]) * gate);
    }
    *(bf16x4*)(y2 + base) = o4;
  }
}

extern "C" void kernel_launch(void* const* d_in, const int* in_sizes, int n_in,
                              void* d_out, int out_size, void* d_ws, size_t ws_size,
                              hipStream_t stream) {
  const float* x     = (const float*)d_in[0];
  const float* decay = (const float*)d_in[3];
  const float* Wq    = (const float*)d_in[4];
  const float* Wv    = (const float*)d_in[5];
  const float* Wo    = (const float*)d_in[6];
  const float* Wg    = (const float*)d_in[7];
  const float* lng   = (const float*)d_in[8];
  const float* lnb   = (const float*)d_in[9];
  float* out = (float*)d_out;

  char* ws = (char*)d_ws;
  size_t off = 0;
  auto alloc = [&](size_t bytes) -> void* {
    void* p = ws + off;
    off += (bytes + 255) & ~(size_t)255;
    return p;
  };
  __bf16* xb   = (__bf16*)alloc(MD * 2);        // x in bf16
  __bf16* w4   = (__bf16*)alloc(4 * DD * 2);    // Wq|Wv|Wg|Wo in bf16
  __bf16* qvg  = (__bf16*)alloc(3 * MD * 2);    // q|v|g
  __bf16* y2b  = (__bf16*)alloc(MD * 2);        // post-LN*gate in bf16
  float*  csum = (float*)alloc((size_t)NCH * NCHAIN * 4);
  float*  cry  = (float*)alloc((size_t)NCH * NCHAIN * 4);

  cvt_bf16<<<(int)(MD / 1024), 256, 0, stream>>>(x, xb);
  cvt_w<<<dim3((unsigned)(DD / 1024), 1, 4), 256, 0, stream>>>(Wq, Wv, Wg, Wo, w4);

  gemm_nt<__bf16><<<dim3(4, MROWS / 256, 3), 512, 0, stream>>>(xb, w4, qvg);

  scan_sum<<<(BATCH * NCH * (DM / 4)) / 256, 256, 0, stream>>>(qvg + MD, csum, decay);
  scan2<<<(NCHAIN / 4) / 256, 256, 0, stream>>>(csum, cry, decay);

  fuse_chunk<<<BATCH * NCH, 256, 0, stream>>>(qvg, qvg + MD, qvg + 2 * MD, cry,
                                              decay, lng, lnb, y2b);

  gemm_nt<float><<<dim3(4, MROWS / 256, 1), 512, 0, stream>>>(y2b, w4 + 3 * DD, out);
}

// Round 4
// 215.385 us; speedup vs baseline: 1.3613x; 1.0003x over previous
//
#include <hip/hip_runtime.h>

// ---- problem constants ----
#define DM    1024
#define LSEQ  4096
#define BATCH 4
#define MROWS (BATCH * LSEQ)           // 16384 rows
#define MD    ((size_t)MROWS * DM)     // 16,777,216 elems
#define DD    ((size_t)DM * DM)        // 1,048,576 elems
#define CHUNK 32
#define NCH   (LSEQ / CHUNK)           // 128 chunks
#define NCHAIN (BATCH * DM)            // 4096 scan chains

typedef __attribute__((ext_vector_type(4))) float  f32x4;
typedef __attribute__((ext_vector_type(8))) __bf16 bf16x8;
typedef __attribute__((ext_vector_type(4))) __bf16 bf16x4;

__device__ __forceinline__ void gload_lds16(const void* g, void* l) {
  __builtin_amdgcn_global_load_lds(
      (const __attribute__((address_space(1))) void*)g,
      (__attribute__((address_space(3))) void*)l, 16, 0, 0);
}

// ---- fp32 -> bf16 converts ----
__global__ __launch_bounds__(256) void cvt_bf16(const float* __restrict__ in,
                                                __bf16* __restrict__ out) {
  size_t i = ((size_t)blockIdx.x * 256 + threadIdx.x) * 4;
  f32x4 f = *(const f32x4*)(in + i);
  bf16x4 o;
#pragma unroll
  for (int j = 0; j < 4; ++j) o[j] = (__bf16)f[j];
  *(bf16x4*)(out + i) = o;
}

__global__ __launch_bounds__(256) void cvt_w(const float* __restrict__ s0,
                                             const float* __restrict__ s1,
                                             const float* __restrict__ s2,
                                             const float* __restrict__ s3,
                                             __bf16* __restrict__ dst) {
  const float* sp = (blockIdx.z == 0) ? s0 : (blockIdx.z == 1) ? s1
                  : (blockIdx.z == 2) ? s2 : s3;
  size_t i = ((size_t)blockIdx.x * 256 + threadIdx.x) * 4;
  f32x4 f = *(const f32x4*)(sp + i);
  bf16x4 o;
#pragma unroll
  for (int j = 0; j < 4; ++j) o[j] = (__bf16)f[j];
  *(bf16x4*)(dst + (size_t)blockIdx.z * DD + i) = o;
}

// ======================= 256x256 relaxed 4-phase bf16 NT GEMM ===============
// C[m][n] = sum_k A[m][k] * W[n][k].  M=16384, N=K=1024.
// 8 waves (2Mx4N), BK=64, 128KiB LDS double-buffered.
// LDS halves aligned to phase readers (A: mh*128+wr*64+r64; B: nh*128+wc*32+r32).
// ONE barrier per phase (post-MFMA, fused with counted vmcnt in a single asm).
// No lgkmcnt(0)/sched_barrier lockstep: compiler interleaves ds_read waits
// into the MFMA stream; waves stagger so one wave's MFMA covers another's
// ds_read drain. Region safety: a phase's LDS readers complete before the
// phase-end barrier (MFMAs consumed them); stages into that region are only
// issued after that barrier.

__device__ __forceinline__ int swz(int b) { return b ^ ((b >> 3) & 0x70); }

__device__ __forceinline__ bf16x8 ldf(const char* tile, int row, int k) {
  int lin = (row << 7) + (k << 1);
  return *(const bf16x8*)(tile + swz(lin));
}

__device__ __forceinline__ void stageA_half(const __bf16* Abase, char* tileA,
                                            int h, int k0, int t) {
#pragma unroll
  for (int is = 0; is < 2; ++is) {
    int d = h * 16384 + is * 8192 + t * 16;
    int l = swz(d);
    int lds_r = l >> 7, cb = l & 127;
    int g = ((lds_r >> 6) & 1) * 128 + h * 64 + (lds_r & 63);   // wr*128+h*64+r64
    gload_lds16((const char*)Abase + (size_t)g * (DM * 2) + k0 * 2 + cb, tileA + d);
  }
}
__device__ __forceinline__ void stageB_half(const __bf16* Bbase, char* tileB,
                                            int h, int k0, int t) {
#pragma unroll
  for (int is = 0; is < 2; ++is) {
    int d = h * 16384 + is * 8192 + t * 16;
    int l = swz(d);
    int lds_r = l >> 7, cb = l & 127;
    int g = ((lds_r >> 5) & 3) * 64 + h * 32 + (lds_r & 31);    // wc*64+h*32+r32
    gload_lds16((const char*)Bbase + (size_t)g * (DM * 2) + k0 * 2 + cb, tileB + d);
  }
}

template <typename OutT>
__global__ __launch_bounds__(512, 2) void gemm_nt(const __bf16* __restrict__ A,
                                                  const __bf16* __restrict__ Wb,
                                                  OutT* __restrict__ Cb) {
  constexpr int K = DM, N = DM, NT = K / 64;
  __shared__ __attribute__((aligned(128))) char lds[131072];

  const __bf16* Wp = Wb + (size_t)blockIdx.z * DD;
  OutT* Cp = Cb + (size_t)blockIdx.z * MD;

  // bijective XCD swizzle: nwg = 4*64 = 256, divisible by 8
  const int orig = blockIdx.y * 4 + blockIdx.x;
  const int sid = (orig & 7) * 32 + (orig >> 3);
  const int bx = sid & 3, by = sid >> 2;
  const int m0 = by * 256, n0 = bx * 256;

  const int t = threadIdx.x, lane = t & 63, wv = t >> 6;
  const int wr = wv >> 2, wc = wv & 3;          // 2 x 4 waves
  const int lrow = lane & 15, lk8 = (lane >> 4) * 8;

  const __bf16* Abase = A + (size_t)m0 * K;
  const __bf16* Bbase = Wp + (size_t)n0 * K;

  f32x4 acc[8][4] = {};
  bf16x8 a[4][2];        // current A mh-half frags
  bf16x8 bq[2][2][2];    // B frags [nh][nf][ks]

  char* buf0 = lds;             // A at +0, B at +32768 within each buf
  char* buf1 = lds + 65536;

  // prologue: kt0 halves {A0,B0,B1,A1} then kt1 same order (16 insts)
  stageA_half(Abase, buf0,         0, 0, t);
  stageB_half(Bbase, buf0 + 32768, 0, 0, t);
  stageB_half(Bbase, buf0 + 32768, 1, 0, t);
  stageA_half(Abase, buf0,         1, 0, t);
  stageA_half(Abase, buf1,         0, 64, t);
  stageB_half(Bbase, buf1 + 32768, 0, 64, t);
  stageB_half(Bbase, buf1 + 32768, 1, 64, t);
  stageA_half(Abase, buf1,         1, 64, t);
  asm volatile("s_waitcnt vmcnt(12)\n\ts_barrier" ::: "memory");

#define LDA_(mh)                                                        \
  _Pragma("unroll") for (int mf = 0; mf < 4; ++mf)                      \
  _Pragma("unroll") for (int ks = 0; ks < 2; ++ks)                      \
    a[mf][ks] = ldf(At, (mh) * 128 + wr * 64 + mf * 16 + lrow, ks * 32 + lk8);
#define LDB_(nh)                                                        \
  _Pragma("unroll") for (int nf = 0; nf < 2; ++nf)                      \
  _Pragma("unroll") for (int ks = 0; ks < 2; ++ks)                      \
    bq[nh][nf][ks] = ldf(Bt, (nh) * 128 + wc * 32 + nf * 16 + lrow, ks * 32 + lk8);
#define MFMA16_(mh, nh)                                                 \
  __builtin_amdgcn_s_setprio(1);                                        \
  _Pragma("unroll") for (int mf = 0; mf < 4; ++mf)                      \
  _Pragma("unroll") for (int nf = 0; nf < 2; ++nf)                      \
  _Pragma("unroll") for (int ks = 0; ks < 2; ++ks)                      \
    acc[(mh) * 4 + mf][(nh) * 2 + nf] = __builtin_amdgcn_mfma_f32_16x16x32_bf16( \
        a[mf][ks], bq[nh][nf][ks], acc[(mh) * 4 + mf][(nh) * 2 + nf], 0, 0, 0); \
  __builtin_amdgcn_s_setprio(0);
#define VMBAR_(n)                                                       \
  asm volatile("s_waitcnt vmcnt(" #n ")\n\ts_barrier" ::: "memory");
#define BAR_                                                            \
  asm volatile("s_barrier" ::: "memory");

#pragma unroll 1
  for (int kt = 0; kt < NT; ++kt) {
    char* bufc = lds + (kt & 1) * 65536;
    const char* At = bufc;
    const char* Bt = bufc + 32768;
    const int k2 = (kt + 2) << 6;
    const bool s2 = (kt + 2 < NT);

    // P1: ds A0+B0; MFMA(0,0); wait (kt)B1
    LDA_(0); LDB_(0);
    MFMA16_(0, 0);
    if (kt < NT - 1) { VMBAR_(10); } else { VMBAR_(2); }

    // P2: stage kt+2 {A0,B0} into dead regions; ds B1; MFMA(0,1); wait (kt)A1
    if (s2) {
      stageA_half(Abase, bufc,         0, k2, t);
      stageB_half(Bbase, bufc + 32768, 0, k2, t);
    }
    LDB_(1);
    MFMA16_(0, 1);
    if (s2) { VMBAR_(12); } else if (kt == NT - 2) { VMBAR_(8); } else { VMBAR_(0); }

    // P3: stage kt+2 B1; ds A1; MFMA(1,0); barrier
    if (s2) stageB_half(Bbase, bufc + 32768, 1, k2, t);
    LDA_(1);
    MFMA16_(1, 0);
    BAR_;

    // P4: stage kt+2 A1; regs-only MFMA; wait (kt+1){A0,B0}
    if (s2) stageA_half(Abase, bufc, 1, k2, t);
    MFMA16_(1, 1);
    if (s2) { VMBAR_(12); } else if (kt == NT - 2) { VMBAR_(4); } else { VMBAR_(0); }
  }
#undef LDA_
#undef LDB_
#undef MFMA16_
#undef VMBAR_
#undef BAR_

  // epilogue: C/D layout col=lane&15, row=(lane>>4)*4+j
#pragma unroll
  for (int mi = 0; mi < 8; ++mi) {
    int r0 = m0 + wr * 128 + (mi >> 2) * 64 + (mi & 3) * 16 + (lane >> 4) * 4;
#pragma unroll
    for (int ni = 0; ni < 4; ++ni) {
      int c0 = n0 + wc * 64 + (ni >> 1) * 32 + (ni & 1) * 16 + (lane & 15);
#pragma unroll
      for (int j = 0; j < 4; ++j) {
        float v = acc[mi][ni][j];
        if constexpr (__is_same(OutT, float))
          Cp[(size_t)(r0 + j) * N + c0] = v;
        else
          Cp[(size_t)(r0 + j) * N + c0] = (__bf16)v;
      }
    }
  }
}

// ---- chunk sums: csum[c][chain] = sum_t lam^(31-t) v_t over chunk c ----
__global__ __launch_bounds__(256) void scan_sum(const __bf16* __restrict__ v,
                                                float* __restrict__ csum,
                                                const float* __restrict__ decay) {
  int tid = blockIdx.x * 256 + threadIdx.x;
  int dg = tid & 255;
  int b  = (tid >> 8) & 3;
  int c  = tid >> 10;
  int d0 = dg * 4;
  float lam = decay[((d0 >> 6) << 1) + 1];
  f32x4 s = {0.f, 0.f, 0.f, 0.f};
  size_t base = ((size_t)b * LSEQ + (size_t)c * CHUNK) * DM + d0;
  for (int t = 0; t < CHUNK; ++t) {
    bf16x4 vv = *(const bf16x4*)(v + base);
    f32x4 vf = {(float)vv[0], (float)vv[1], (float)vv[2], (float)vv[3]};
    s = lam * s + vf;
    base += DM;
  }
  *(f32x4*)(csum + (size_t)c * NCHAIN + b * DM + d0) = s;
}

// ---- pass2: carry[c][chain] = full state entering chunk c ----
__global__ __launch_bounds__(256) void scan2(const float* __restrict__ csum,
                                             float* __restrict__ carry,
                                             const float* __restrict__ decay) {
  int i = blockIdx.x * 256 + threadIdx.x;
  int ch0 = i * 4;
  int d0 = ch0 & (DM - 1);
  float lam = decay[((d0 >> 6) << 1) + 1];
  float l2 = lam * lam, l4 = l2 * l2, l8 = l4 * l4, l16 = l8 * l8;
  float lamC = l16 * l16;
  f32x4 cs = {0.f, 0.f, 0.f, 0.f};
  for (int c = 0; c < NCH; ++c) {
    *(f32x4*)(carry + (size_t)c * NCHAIN + ch0) = cs;
    f32x4 sm = *(const f32x4*)(csum + (size_t)c * NCHAIN + ch0);
    cs = lamC * cs + sm;
  }
}

// ---- fused per-chunk: exact scan (carry-seeded) + y=q*s + LN + silu gate ----
__global__ __launch_bounds__(256) void fuse_chunk(
    const __bf16* __restrict__ qb, const __bf16* __restrict__ vb,
    const __bf16* __restrict__ gb, const float* __restrict__ carry,
    const float* __restrict__ decay, const float* __restrict__ ln_g,
    const float* __restrict__ ln_b, __bf16* __restrict__ y2) {
  const int blk = blockIdx.x;
  const int b = blk >> 7, c = blk & 127;
  const int t = threadIdx.x, lane = t & 63, wv = t >> 6;
  const int d0 = t * 4;
  const float lam = decay[((d0 >> 6) << 1) + 1];
  f32x4 s = *(const f32x4*)(carry + (size_t)c * NCHAIN + b * DM + d0);
  const size_t base0 = ((size_t)b * LSEQ + (size_t)c * CHUNK) * DM + d0;

  __shared__ float sbs[2][32][4];
  __shared__ float stats[32][2];

  f32x4 y[32];
#pragma unroll
  for (int r = 0; r < 32; ++r) {
    size_t base = base0 + (size_t)r * DM;
    bf16x4 v4 = *(const bf16x4*)(vb + base);
    bf16x4 q4 = *(const bf16x4*)(qb + base);
    f32x4 vf = {(float)v4[0], (float)v4[1], (float)v4[2], (float)v4[3]};
    s = lam * s + vf;
    f32x4 yy;
    float su = 0.f, sq = 0.f;
#pragma unroll
    for (int i = 0; i < 4; ++i) {
      float val = (float)q4[i] * s[i];
      yy[i] = val; su += val; sq += val * val;
    }
    y[r] = yy;
#pragma unroll
    for (int o = 32; o > 0; o >>= 1) {
      su += __shfl_xor(su, o);
      sq += __shfl_xor(sq, o);
    }
    if (lane == 0) { sbs[0][r][wv] = su; sbs[1][r][wv] = sq; }
  }
  __syncthreads();
  if (t < 32) {
    float su = sbs[0][t][0] + sbs[0][t][1] + sbs[0][t][2] + sbs[0][t][3];
    float sq = sbs[1][t][0] + sbs[1][t][1] + sbs[1][t][2] + sbs[1][t][3];
    float mu = su * (1.0f / DM);
    float var = sq * (1.0f / DM) - mu * mu;
    stats[t][0] = mu;
    stats[t][1] = rsqrtf(fmaxf(var, 0.0f) + 1e-5f);
  }
  __syncthreads();

  f32x4 lg = *(const f32x4*)(ln_g + d0);
  f32x4 lb = *(const f32x4*)(ln_b + d0);
#pragma unroll
  for (int r = 0; r < 32; ++r) {
    size_t base = base0 + (size_t)r * DM;
    bf16x4 g4 = *(const bf16x4*)(gb + base);
    const float mu = stats[r][0], rstd = stats[r][1];
    bf16x4 o4;
#pragma unroll
    for (int i = 0; i < 4; ++i) {
      float gv = (float)g4[i];
      float gate = gv / (1.0f + __expf(-gv));
      o4[i] = (__bf16)(fmaf((y[r][i] - mu) * rstd, lg[i], lb[i]) * gate);
    }
    *(bf16x4*)(y2 + base) = o4;
  }
}

extern "C" void kernel_launch(void* const* d_in, const int* in_sizes, int n_in,
                              void* d_out, int out_size, void* d_ws, size_t ws_size,
                              hipStream_t stream) {
  const float* x     = (const float*)d_in[0];
  const float* decay = (const float*)d_in[3];
  const float* Wq    = (const float*)d_in[4];
  const float* Wv    = (const float*)d_in[5];
  const float* Wo    = (const float*)d_in[6];
  const float* Wg    = (const float*)d_in[7];
  const float* lng   = (const float*)d_in[8];
  const float* lnb   = (const float*)d_in[9];
  float* out = (float*)d_out;

  char* ws = (char*)d_ws;
  size_t off = 0;
  auto alloc = [&](size_t bytes) -> void* {
    void* p = ws + off;
    off += (bytes + 255) & ~(size_t)255;
    return p;
  };
  __bf16* xb   = (__bf16*)alloc(MD * 2);        // x in bf16
  __bf16* w4   = (__bf16*)alloc(4 * DD * 2);    // Wq|Wv|Wg|Wo in bf16
  __bf16* qvg  = (__bf16*)alloc(3 * MD * 2);    // q|v|g
  __bf16* y2b  = (__bf16*)alloc(MD * 2);        // post-LN*gate in bf16
  float*  csum = (float*)alloc((size_t)NCH * NCHAIN * 4);
  float*  cry  = (float*)alloc((size_t)NCH * NCHAIN * 4);

  cvt_bf16<<<(int)(MD / 1024), 256, 0, stream>>>(x, xb);
  cvt_w<<<dim3((unsigned)(DD / 1024), 1, 4), 256, 0, stream>>>(Wq, Wv, Wg, Wo, w4);

  gemm_nt<__bf16><<<dim3(4, MROWS / 256, 3), 512, 0, stream>>>(xb, w4, qvg);

  scan_sum<<<(BATCH * NCH * (DM / 4)) / 256, 256, 0, stream>>>(qvg + MD, csum, decay);
  scan2<<<(NCHAIN / 4) / 256, 256, 0, stream>>>(csum, cry, decay);

  fuse_chunk<<<BATCH * NCH, 256, 0, stream>>>(qvg, qvg + MD, qvg + 2 * MD, cry,
                                              decay, lng, lnb, y2b);

  gemm_nt<float><<<dim3(4, MROWS / 256, 1), 512, 0, stream>>>(y2b, w4 + 3 * DD, out);
}